// Round 2
// baseline (690.256 us; speedup 1.0000x reference)
//
#include <hip/hip_runtime.h>
#include <math.h>

#define NNS 16
#define CIN 64
#define COUT 64
#define CS 8
#define EPSB 1e-5f

// ---------------- Kernel 1: QKV projection ----------------
// (n x 64) @ (64 x 192) fused; W staged in LDS; one wave per row, lane = channel.
__global__ __launch_bounds__(256) void qkv_kernel(
    const float* __restrict__ x,
    const float* __restrict__ Wq, const float* __restrict__ bq,
    const float* __restrict__ Wk, const float* __restrict__ bk,
    const float* __restrict__ Wv, const float* __restrict__ bv,
    float* __restrict__ xq, float* __restrict__ xk, float* __restrict__ xv,
    int n)
{
    __shared__ float W[CIN * 192];  // [u][m*64+c], m=0:q 1:k 2:v  (48 KB)
    for (int i = threadIdx.x; i < CIN * 192; i += 256) {
        int u = i / 192;
        int r = i - u * 192;
        int m = r >> 6;
        int c = r & 63;
        const float* Ws = (m == 0) ? Wq : (m == 1) ? Wk : Wv;
        W[i] = Ws[u * COUT + c];
    }
    __syncthreads();
    const int lane = threadIdx.x & 63;
    const int wid  = __builtin_amdgcn_readfirstlane((int)(threadIdx.x >> 6));
    const float bqc = bq[lane], bkc = bk[lane], bvc = bv[lane];
    const int nw = gridDim.x * 4;
    for (int i = blockIdx.x * 4 + wid; i < n; i += nw) {
        const float* xr = x + (size_t)i * CIN;
        float aq = bqc, ak = bkc, av = bvc;
        #pragma unroll
        for (int u = 0; u < CIN; ++u) {
            const float xu = xr[u];  // uniform -> scalar load
            aq = fmaf(xu, W[u * 192 + lane], aq);
            ak = fmaf(xu, W[u * 192 + 64 + lane], ak);
            av = fmaf(xu, W[u * 192 + 128 + lane], av);
        }
        xq[(size_t)i * COUT + lane] = aq;
        xk[(size_t)i * COUT + lane] = ak;
        xv[(size_t)i * COUT + lane] = av;
    }
}

// ---------------- Kernel 2: fused neighbor attention ----------------
// One wave per point. lane = channel c. s = lane>>3 (reduce-target slot),
// sc = lane&7 (softmax slot used by channel c). Online softmax over neighbors.
__global__ __launch_bounds__(256) void fused_kernel(
    const float* __restrict__ p, const int* __restrict__ idx,
    const float* __restrict__ xq, const float* __restrict__ xk, const float* __restrict__ xv,
    const float* __restrict__ Wp1, const float* __restrict__ bp1,
    const float* __restrict__ bnp_g, const float* __restrict__ bnp_b,
    const float* __restrict__ bnp_m, const float* __restrict__ bnp_v,
    const float* __restrict__ Wp2, const float* __restrict__ bp2,
    const float* __restrict__ bnw1_g, const float* __restrict__ bnw1_b,
    const float* __restrict__ bnw1_m, const float* __restrict__ bnw1_v,
    const float* __restrict__ Ww1, const float* __restrict__ bw1,
    const float* __restrict__ bnw2_g, const float* __restrict__ bnw2_b,
    const float* __restrict__ bnw2_m, const float* __restrict__ bnw2_v,
    const float* __restrict__ Ww2, const float* __restrict__ bw2,
    float* __restrict__ out, int n)
{
    const int lane = threadIdx.x & 63;
    const int sc   = lane & 7;
    const bool b3 = lane & 8, b4 = lane & 16, b5 = lane & 32;

    // linear_p stage-1 params (uniform across lanes)
    float wp1[9];
    #pragma unroll
    for (int t = 0; t < 9; ++t) wp1[t] = Wp1[t];
    float ap[3], cp[3];
    #pragma unroll
    for (int t = 0; t < 3; ++t) {
        const float a = bnp_g[t] * rsqrtf(bnp_v[t] + EPSB);
        ap[t] = a;
        cp[t] = (bp1[t] - bnp_m[t]) * a + bnp_b[t];   // fold bp1 + BN shift
    }
    // per-channel params
    const float wp2_0 = Wp2[0 * COUT + lane];
    const float wp2_1 = Wp2[1 * COUT + lane];
    const float wp2_2 = Wp2[2 * COUT + lane];
    const float bp2c  = bp2[lane];
    const float a1 = bnw1_g[lane] * rsqrtf(bnw1_v[lane] + EPSB);
    const float c1 = bnw1_b[lane] - bnw1_m[lane] * a1;
    float ww1[8];
    #pragma unroll
    for (int t = 0; t < 8; ++t) ww1[t] = Ww1[lane * CS + t];
    // slot-indexed params (each lane holds all 8)
    float a2v[8], c2v[8], ww2c[8];
    #pragma unroll
    for (int q = 0; q < 8; ++q) {
        const float a = bnw2_g[q] * rsqrtf(bnw2_v[q] + EPSB);
        a2v[q] = a;
        c2v[q] = bnw2_b[q] + (bw1[q] - bnw2_m[q]) * a;  // fold bw1 + BN shift
        ww2c[q] = Ww2[q * CS + sc];
    }
    const float bw2sc = bw2[sc];

    const int wid = __builtin_amdgcn_readfirstlane((int)(threadIdx.x >> 6));
    const int i = blockIdx.x * 4 + wid;
    if (i < n) {
        const float xqc = xq[(size_t)i * COUT + lane];
        const float pix = p[i * 3 + 0];
        const float piy = p[i * 3 + 1];
        const float piz = p[i * 3 + 2];
        const int myidx = idx[i * NNS + (lane & 15)];
        float m = -INFINITY, den = 0.f, acc = 0.f;
        #pragma unroll
        for (int k = 0; k < NNS; ++k) {
            const int j = __builtin_amdgcn_readfirstlane(__shfl(myidx, k, 64));
            const float gx0 = p[j * 3 + 0] - pix;
            const float gx1 = p[j * 3 + 1] - piy;
            const float gx2 = p[j * 3 + 2] - piz;
            const float xkc = xk[(size_t)j * COUT + lane];
            const float xvc = xv[(size_t)j * COUT + lane];
            // position MLP (uniform, computed redundantly per lane)
            float h0 = fmaf(gx2, wp1[6], fmaf(gx1, wp1[3], gx0 * wp1[0]));
            float h1 = fmaf(gx2, wp1[7], fmaf(gx1, wp1[4], gx0 * wp1[1]));
            float h2 = fmaf(gx2, wp1[8], fmaf(gx1, wp1[5], gx0 * wp1[2]));
            h0 = fmaxf(0.f, fmaf(h0, ap[0], cp[0]));
            h1 = fmaxf(0.f, fmaf(h1, ap[1], cp[1]));
            h2 = fmaxf(0.f, fmaf(h2, ap[2], cp[2]));
            const float pr = fmaf(h2, wp2_2, fmaf(h1, wp2_1, fmaf(h0, wp2_0, bp2c)));
            const float wv = xkc - xqc + pr;
            const float wb = fmaxf(0.f, fmaf(wv, a1, c1));
            // products for the (64 -> 8) matvec
            const float P0 = wb * ww1[0], P1 = wb * ww1[1], P2 = wb * ww1[2], P3 = wb * ww1[3];
            const float P4 = wb * ww1[4], P5 = wb * ww1[5], P6 = wb * ww1[6], P7 = wb * ww1[7];
            // reduce-scatter butterfly: lane ends with full sum for s = lane>>3
            float Q0 = (b5 ? P4 : P0) + __shfl_xor(b5 ? P0 : P4, 32, 64);
            float Q1 = (b5 ? P5 : P1) + __shfl_xor(b5 ? P1 : P5, 32, 64);
            float Q2 = (b5 ? P6 : P2) + __shfl_xor(b5 ? P2 : P6, 32, 64);
            float Q3 = (b5 ? P7 : P3) + __shfl_xor(b5 ? P3 : P7, 32, 64);
            float R0 = (b4 ? Q2 : Q0) + __shfl_xor(b4 ? Q0 : Q2, 16, 64);
            float R1 = (b4 ? Q3 : Q1) + __shfl_xor(b4 ? Q1 : Q3, 16, 64);
            float T  = (b3 ? R1 : R0) + __shfl_xor(b3 ? R0 : R1, 8, 64);
            T += __shfl_xor(T, 4, 64);
            T += __shfl_xor(T, 2, 64);
            T += __shfl_xor(T, 1, 64);
            // broadcast all 8 slot sums, BN2+ReLU+(8x8) locally for slot sc
            float y = bw2sc;
            #pragma unroll
            for (int q = 0; q < 8; ++q) {
                const float l1  = __shfl(T, q << 3, 64);
                const float wb2 = fmaxf(0.f, fmaf(l1, a2v[q], c2v[q]));
                y = fmaf(wb2, ww2c[q], y);
            }
            // online softmax over neighbors for slot sc
            const float mn = fmaxf(m, y);
            const float al = __expf(m - mn);   // 0 on first iter (m = -inf)
            const float e  = __expf(y - mn);
            den = fmaf(den, al, e);
            acc = fmaf(acc, al, e * (xvc + pr));
            m = mn;
        }
        out[(size_t)i * COUT + lane] = acc / den;
    }
}

extern "C" void kernel_launch(void* const* d_in, const int* in_sizes, int n_in,
                              void* d_out, int out_size, void* d_ws, size_t ws_size,
                              hipStream_t stream) {
    const float* p     = (const float*)d_in[0];
    const float* x     = (const float*)d_in[1];
    const int*   idx   = (const int*)  d_in[2];
    const float* Wq    = (const float*)d_in[3];
    const float* bq    = (const float*)d_in[4];
    const float* Wk    = (const float*)d_in[5];
    const float* bk    = (const float*)d_in[6];
    const float* Wv    = (const float*)d_in[7];
    const float* bv    = (const float*)d_in[8];
    const float* Wp1   = (const float*)d_in[9];
    const float* bp1   = (const float*)d_in[10];
    const float* bnp_g = (const float*)d_in[11];
    const float* bnp_b = (const float*)d_in[12];
    const float* bnp_m = (const float*)d_in[13];
    const float* bnp_v = (const float*)d_in[14];
    const float* Wp2   = (const float*)d_in[15];
    const float* bp2   = (const float*)d_in[16];
    const float* bnw1_g= (const float*)d_in[17];
    const float* bnw1_b= (const float*)d_in[18];
    const float* bnw1_m= (const float*)d_in[19];
    const float* bnw1_v= (const float*)d_in[20];
    const float* Ww1   = (const float*)d_in[21];
    const float* bw1   = (const float*)d_in[22];
    const float* bnw2_g= (const float*)d_in[23];
    const float* bnw2_b= (const float*)d_in[24];
    const float* bnw2_m= (const float*)d_in[25];
    const float* bnw2_v= (const float*)d_in[26];
    const float* Ww2   = (const float*)d_in[27];
    const float* bw2   = (const float*)d_in[28];

    const int n = in_sizes[0] / 3;   // N points

    float* xq = (float*)d_ws;
    float* xk = xq + (size_t)n * COUT;
    float* xv = xk + (size_t)n * COUT;

    hipLaunchKernelGGL(qkv_kernel, dim3(2048), dim3(256), 0, stream,
                       x, Wq, bq, Wk, bk, Wv, bv, xq, xk, xv, n);
    hipLaunchKernelGGL(fused_kernel, dim3((n + 3) / 4), dim3(256), 0, stream,
                       p, idx, xq, xk, xv,
                       Wp1, bp1, bnp_g, bnp_b, bnp_m, bnp_v, Wp2, bp2,
                       bnw1_g, bnw1_b, bnw1_m, bnw1_v, Ww1, bw1,
                       bnw2_g, bnw2_b, bnw2_m, bnw2_v, Ww2, bw2,
                       (float*)d_out, n);
}

// Round 3
// 534.910 us; speedup vs baseline: 1.2904x; 1.2904x over previous
//
#include <hip/hip_runtime.h>
#include <math.h>

#define NNS 16
#define CIN 64
#define COUT 64
#define CS 8
#define EPSB 1e-5f

static __device__ __forceinline__ float rdlanef(float v, int l) {
    return __builtin_bit_cast(float, __builtin_amdgcn_readlane(__builtin_bit_cast(int, v), l));
}

// ---------------- Kernel 1: QKV projection ----------------
// One wave per row. xrow held per-lane; x[u] broadcast via v_readlane (VALU),
// keeping the lgkm domain exclusively for the LDS weight reads.
__global__ __launch_bounds__(256) void qkv_kernel(
    const float* __restrict__ x,
    const float* __restrict__ Wq, const float* __restrict__ bq,
    const float* __restrict__ Wk, const float* __restrict__ bk,
    const float* __restrict__ Wv, const float* __restrict__ bv,
    float* __restrict__ xq, float* __restrict__ xk, float* __restrict__ xv,
    int n)
{
    __shared__ float W[CIN * 192];  // [u][m*64+c], m=0:q 1:k 2:v  (48 KB)
    for (int t = threadIdx.x; t < CIN * 192; t += 256) {
        int u = t / 192;
        int r = t - u * 192;
        int m = r >> 6;
        int c = r & 63;
        const float* Ws = (m == 0) ? Wq : (m == 1) ? Wk : Wv;
        W[t] = Ws[u * COUT + c];
    }
    __syncthreads();
    const int lane = threadIdx.x & 63;
    const int wid  = __builtin_amdgcn_readfirstlane((int)(threadIdx.x >> 6));
    const int i = blockIdx.x * 4 + wid;
    if (i >= n) return;

    const float xrow = x[(size_t)i * CIN + lane];   // coalesced
    float aq = bq[lane], ak = bk[lane], av = bv[lane];
    #pragma unroll
    for (int u = 0; u < CIN; ++u) {
        const float xu = rdlanef(xrow, u);          // SGPR broadcast, no lgkm
        aq = fmaf(xu, W[u * 192 + lane], aq);
        ak = fmaf(xu, W[u * 192 + 64 + lane], ak);
        av = fmaf(xu, W[u * 192 + 128 + lane], av);
    }
    xq[(size_t)i * COUT + lane] = aq;
    xk[(size_t)i * COUT + lane] = ak;
    xv[(size_t)i * COUT + lane] = av;
}

// ---------------- Kernel 2: fused neighbor attention ----------------
// One wave per point, lane = channel. Mask-free XOR butterfly with
// pre-permuted Ww1; z-contribution + second allreduce replaces the
// broadcast loop; two-pass softmax over registered logits.
__global__ __launch_bounds__(256) void fused_kernel(
    const float* __restrict__ p, const int* __restrict__ idx,
    const float* __restrict__ xq, const float* __restrict__ xk, const float* __restrict__ xv,
    const float* __restrict__ Wp1, const float* __restrict__ bp1,
    const float* __restrict__ bnp_g, const float* __restrict__ bnp_b,
    const float* __restrict__ bnp_m, const float* __restrict__ bnp_v,
    const float* __restrict__ Wp2, const float* __restrict__ bp2,
    const float* __restrict__ bnw1_g, const float* __restrict__ bnw1_b,
    const float* __restrict__ bnw1_m, const float* __restrict__ bnw1_v,
    const float* __restrict__ Ww1, const float* __restrict__ bw1,
    const float* __restrict__ bnw2_g, const float* __restrict__ bnw2_b,
    const float* __restrict__ bnw2_m, const float* __restrict__ bnw2_v,
    const float* __restrict__ Ww2, const float* __restrict__ bw2,
    float* __restrict__ out, int n)
{
    const int lane = threadIdx.x & 63;
    const int s    = (lane >> 3) & 7;   // owned slot after reduce-scatter
    const int r    = lane & 7;          // output-slot this channel consumes (c % 8)

    // ---- wave-uniform params (SGPRs) ----
    float wp1[9];
    #pragma unroll
    for (int t = 0; t < 9; ++t) wp1[t] = Wp1[t];
    float ap[3], cp[3];
    #pragma unroll
    for (int t = 0; t < 3; ++t) {
        const float a = bnp_g[t] * rsqrtf(bnp_v[t] + EPSB);
        ap[t] = a;
        cp[t] = (bp1[t] - bnp_m[t]) * a + bnp_b[t];
    }
    // ---- per-lane params ----
    const float wp2_0 = Wp2[0 * COUT + lane];
    const float wp2_1 = Wp2[1 * COUT + lane];
    const float wp2_2 = Wp2[2 * COUT + lane];
    const float bp2c  = bp2[lane];
    const float a1 = bnw1_g[lane] * rsqrtf(bnw1_v[lane] + EPSB);
    const float c1 = bnw1_b[lane] - bnw1_m[lane] * a1;
    // pre-permuted Ww1: position t holds slot (t ^ s)
    float w1p[8];
    #pragma unroll
    for (int t = 0; t < 8; ++t) w1p[t] = Ww1[lane * CS + (t ^ s)];
    // slot-s BN2 params + Ww2[s][r] == Ww2[lane]
    const float a2s = bnw2_g[s] * rsqrtf(bnw2_v[s] + EPSB);
    const float c2s = bnw2_b[s] + (bw1[s] - bnw2_m[s]) * a2s;
    const float ww2l = Ww2[lane];
    const float bw2r = bw2[r];

    const int wid = __builtin_amdgcn_readfirstlane((int)(threadIdx.x >> 6));
    const int i = blockIdx.x * 4 + wid;
    if (i >= n) return;

    const int myidx = idx[i * NNS + (lane & 15)];
    const float xqc = xq[(size_t)i * COUT + lane];
    const float c1l = c1 - a1 * xqc;    // fold -xq into the BN1 shift
    const float pix = p[i * 3 + 0];
    const float piy = p[i * 3 + 1];
    const float piz = p[i * 3 + 2];

    // gather neighbor positions (lane k holds neighbor k&15's data)
    const float pjx = p[myidx * 3 + 0];
    const float pjy = p[myidx * 3 + 1];
    const float pjz = p[myidx * 3 + 2];

    // prefetch all gather rows (32 VMEM in flight)
    float xkr[NNS], xvr[NNS];
    #pragma unroll
    for (int k = 0; k < NNS; ++k) {
        const int j = __builtin_amdgcn_readlane(myidx, k);
        xkr[k] = xk[(size_t)j * COUT + lane];
        xvr[k] = xv[(size_t)j * COUT + lane];
    }

    // position-MLP hidden layer for neighbor (lane & 15), all lanes uniform per 16
    const float gx0 = pjx - pix, gx1 = pjy - piy, gx2 = pjz - piz;
    float h0 = fmaf(gx2, wp1[6], fmaf(gx1, wp1[3], gx0 * wp1[0]));
    float h1 = fmaf(gx2, wp1[7], fmaf(gx1, wp1[4], gx0 * wp1[1]));
    float h2 = fmaf(gx2, wp1[8], fmaf(gx1, wp1[5], gx0 * wp1[2]));
    h0 = fmaxf(0.f, fmaf(h0, ap[0], cp[0]));
    h1 = fmaxf(0.f, fmaf(h1, ap[1], cp[1]));
    h2 = fmaxf(0.f, fmaf(h2, ap[2], cp[2]));

    float y[NNS];
    float m = -INFINITY;

    #pragma unroll
    for (int k = 0; k < NNS; ++k) {
        // pr for neighbor k at this channel
        const float hk0 = rdlanef(h0, k);
        const float hk1 = rdlanef(h1, k);
        const float hk2 = rdlanef(h2, k);
        const float pr = fmaf(hk2, wp2_2, fmaf(hk1, wp2_1, fmaf(hk0, wp2_0, bp2c)));
        // BN1 + ReLU of (xk - xq + pr)
        const float wb = fmaxf(0.f, fmaf(xkr[k], a1, fmaf(pr, a1, c1l)));
        xvr[k] += pr;                         // (vg + pr), kept for pass 2
        // 64x8 matvec: mask-free XOR reduce-scatter (slot s ends at this lane)
        float P0 = wb * w1p[0], P1 = wb * w1p[1], P2 = wb * w1p[2], P3 = wb * w1p[3];
        float P4 = wb * w1p[4], P5 = wb * w1p[5], P6 = wb * w1p[6], P7 = wb * w1p[7];
        float Q0 = P0 + __shfl_xor(P4, 32, 64);
        float Q1 = P1 + __shfl_xor(P5, 32, 64);
        float Q2 = P2 + __shfl_xor(P6, 32, 64);
        float Q3 = P3 + __shfl_xor(P7, 32, 64);
        float R0 = Q0 + __shfl_xor(Q2, 16, 64);
        float R1 = Q1 + __shfl_xor(Q3, 16, 64);
        float T  = R0 + __shfl_xor(R1, 8, 64);
        // complete S[s] across the octet residues
        T += __shfl_xor(T, 4, 64);
        T += __shfl_xor(T, 2, 64);
        T += __shfl_xor(T, 1, 64);
        // BN2 + ReLU, slot-s contribution to output-slot r, allreduce over s
        const float wb2 = fmaxf(0.f, fmaf(T, a2s, c2s));
        float z = wb2 * ww2l;
        z += __shfl_xor(z, 8, 64);
        z += __shfl_xor(z, 16, 64);
        z += __shfl_xor(z, 32, 64);
        const float yk = z + bw2r;
        y[k] = yk;
        m = fmaxf(m, yk);
    }

    // pass 2: exact softmax + weighted sum
    float den = 0.f, acc = 0.f;
    #pragma unroll
    for (int k = 0; k < NNS; ++k) {
        const float e = __expf(y[k] - m);
        den += e;
        acc = fmaf(e, xvr[k], acc);
    }
    out[(size_t)i * COUT + lane] = acc / den;
}

extern "C" void kernel_launch(void* const* d_in, const int* in_sizes, int n_in,
                              void* d_out, int out_size, void* d_ws, size_t ws_size,
                              hipStream_t stream) {
    const float* p     = (const float*)d_in[0];
    const float* x     = (const float*)d_in[1];
    const int*   idx   = (const int*)  d_in[2];
    const float* Wq    = (const float*)d_in[3];
    const float* bq    = (const float*)d_in[4];
    const float* Wk    = (const float*)d_in[5];
    const float* bk    = (const float*)d_in[6];
    const float* Wv    = (const float*)d_in[7];
    const float* bv    = (const float*)d_in[8];
    const float* Wp1   = (const float*)d_in[9];
    const float* bp1   = (const float*)d_in[10];
    const float* bnp_g = (const float*)d_in[11];
    const float* bnp_b = (const float*)d_in[12];
    const float* bnp_m = (const float*)d_in[13];
    const float* bnp_v = (const float*)d_in[14];
    const float* Wp2   = (const float*)d_in[15];
    const float* bp2   = (const float*)d_in[16];
    const float* bnw1_g= (const float*)d_in[17];
    const float* bnw1_b= (const float*)d_in[18];
    const float* bnw1_m= (const float*)d_in[19];
    const float* bnw1_v= (const float*)d_in[20];
    const float* Ww1   = (const float*)d_in[21];
    const float* bw1   = (const float*)d_in[22];
    const float* bnw2_g= (const float*)d_in[23];
    const float* bnw2_b= (const float*)d_in[24];
    const float* bnw2_m= (const float*)d_in[25];
    const float* bnw2_v= (const float*)d_in[26];
    const float* Ww2   = (const float*)d_in[27];
    const float* bw2   = (const float*)d_in[28];

    const int n = in_sizes[0] / 3;   // N points

    float* xq = (float*)d_ws;
    float* xk = xq + (size_t)n * COUT;
    float* xv = xk + (size_t)n * COUT;

    hipLaunchKernelGGL(qkv_kernel, dim3((n + 3) / 4), dim3(256), 0, stream,
                       x, Wq, bq, Wk, bk, Wv, bv, xq, xk, xv, n);
    hipLaunchKernelGGL(fused_kernel, dim3((n + 3) / 4), dim3(256), 0, stream,
                       p, idx, xq, xk, xv,
                       Wp1, bp1, bnp_g, bnp_b, bnp_m, bnp_v, Wp2, bp2,
                       bnw1_g, bnw1_b, bnw1_m, bnw1_v, Ww1, bw1,
                       bnw2_g, bnw2_b, bnw2_m, bnw2_v, Ww2, bw2,
                       (float*)d_out, n);
}

// Round 5
// 404.167 us; speedup vs baseline: 1.7078x; 1.3235x over previous
//
#include <hip/hip_runtime.h>
#include <math.h>

#define NNS 16
#define CIN 64
#define COUT 64
#define CS 8
#define EPSB 1e-5f

static __device__ __forceinline__ float rdlanef(float v, int l) {
    return __builtin_bit_cast(float, __builtin_amdgcn_readlane(__builtin_bit_cast(int, v), l));
}

// ---------------- Kernel 1: QKV projection ----------------
// One wave per row-chunk, lane = output channel. All 192 weight columns live
// in VGPRs (static indexing, fully unrolled). Inner loop: 1 coalesced load,
// 64 readlane broadcasts + 192 FMA, 3 coalesced stores. No LDS at all.
__global__ __launch_bounds__(256, 2) void qkv_kernel(
    const float* __restrict__ x,
    const float* __restrict__ Wq, const float* __restrict__ bq,
    const float* __restrict__ Wk, const float* __restrict__ bk,
    const float* __restrict__ Wv, const float* __restrict__ bv,
    float* __restrict__ xq, float* __restrict__ xk, float* __restrict__ xv,
    int n)
{
    const int lane = threadIdx.x & 63;
    const int wave = blockIdx.x * 4 + (threadIdx.x >> 6);
    const int nwaves = gridDim.x * 4;

    // weights into VGPRs (coalesced; amortized over the row chunk)
    float wq[CIN], wk[CIN], wv[CIN];
    #pragma unroll
    for (int u = 0; u < CIN; ++u) {
        wq[u] = Wq[u * COUT + lane];
        wk[u] = Wk[u * COUT + lane];
        wv[u] = Wv[u * COUT + lane];
    }
    const float bqc = bq[lane], bkc = bk[lane], bvc = bv[lane];

    const int chunk = (n + nwaves - 1) / nwaves;
    const int r0 = wave * chunk;
    const int r1 = (r0 + chunk < n) ? (r0 + chunk) : n;
    if (r0 >= n) return;

    float xcur = x[(size_t)r0 * CIN + lane];
    for (int i = r0; i < r1; ++i) {
        const float xnext = (i + 1 < r1) ? x[(size_t)(i + 1) * CIN + lane] : 0.f;
        float aq = bqc, ak = bkc, av = bvc;
        #pragma unroll
        for (int u = 0; u < CIN; ++u) {
            const float xu = rdlanef(xcur, u);   // SGPR broadcast, VALU only
            aq = fmaf(xu, wq[u], aq);
            ak = fmaf(xu, wk[u], ak);
            av = fmaf(xu, wv[u], av);
        }
        xq[(size_t)i * COUT + lane] = aq;
        xk[(size_t)i * COUT + lane] = ak;
        xv[(size_t)i * COUT + lane] = av;
        xcur = xnext;
    }
}

// ---------------- Kernel 2: fused neighbor attention ----------------
// One wave per point, lane = channel. Mask-free XOR butterfly with
// pre-permuted Ww1; z-contribution + second allreduce replaces the
// broadcast loop; two-pass softmax over registered logits.
__global__ __launch_bounds__(256) void fused_kernel(
    const float* __restrict__ p, const int* __restrict__ idx,
    const float* __restrict__ xq, const float* __restrict__ xk, const float* __restrict__ xv,
    const float* __restrict__ Wp1, const float* __restrict__ bp1,
    const float* __restrict__ bnp_g, const float* __restrict__ bnp_b,
    const float* __restrict__ bnp_m, const float* __restrict__ bnp_v,
    const float* __restrict__ Wp2, const float* __restrict__ bp2,
    const float* __restrict__ bnw1_g, const float* __restrict__ bnw1_b,
    const float* __restrict__ bnw1_m, const float* __restrict__ bnw1_v,
    const float* __restrict__ Ww1, const float* __restrict__ bw1,
    const float* __restrict__ bnw2_g, const float* __restrict__ bnw2_b,
    const float* __restrict__ bnw2_m, const float* __restrict__ bnw2_v,
    const float* __restrict__ Ww2, const float* __restrict__ bw2,
    float* __restrict__ out, int n)
{
    const int lane = threadIdx.x & 63;
    const int s    = (lane >> 3) & 7;   // owned slot after reduce-scatter
    const int r    = lane & 7;          // output-slot this channel consumes (c % 8)

    // ---- wave-uniform params (SGPRs) ----
    float wp1[9];
    #pragma unroll
    for (int t = 0; t < 9; ++t) wp1[t] = Wp1[t];
    float ap[3], cp[3];
    #pragma unroll
    for (int t = 0; t < 3; ++t) {
        const float a = bnp_g[t] * rsqrtf(bnp_v[t] + EPSB);
        ap[t] = a;
        cp[t] = (bp1[t] - bnp_m[t]) * a + bnp_b[t];
    }
    // ---- per-lane params ----
    const float wp2_0 = Wp2[0 * COUT + lane];
    const float wp2_1 = Wp2[1 * COUT + lane];
    const float wp2_2 = Wp2[2 * COUT + lane];
    const float bp2c  = bp2[lane];
    const float a1 = bnw1_g[lane] * rsqrtf(bnw1_v[lane] + EPSB);
    const float c1 = bnw1_b[lane] - bnw1_m[lane] * a1;
    // pre-permuted Ww1: position t holds slot (t ^ s)
    float w1p[8];
    #pragma unroll
    for (int t = 0; t < 8; ++t) w1p[t] = Ww1[lane * CS + (t ^ s)];
    // slot-s BN2 params + Ww2[s][r] == Ww2[lane]
    const float a2s = bnw2_g[s] * rsqrtf(bnw2_v[s] + EPSB);
    const float c2s = bnw2_b[s] + (bw1[s] - bnw2_m[s]) * a2s;
    const float ww2l = Ww2[lane];
    const float bw2r = bw2[r];

    const int wid = __builtin_amdgcn_readfirstlane((int)(threadIdx.x >> 6));
    const int i = blockIdx.x * 4 + wid;
    if (i >= n) return;

    const int myidx = idx[i * NNS + (lane & 15)];
    const float xqc = xq[(size_t)i * COUT + lane];
    const float c1l = c1 - a1 * xqc;    // fold -xq into the BN1 shift
    const float pix = p[i * 3 + 0];
    const float piy = p[i * 3 + 1];
    const float piz = p[i * 3 + 2];

    // gather neighbor positions (lane k holds neighbor k&15's data)
    const float pjx = p[myidx * 3 + 0];
    const float pjy = p[myidx * 3 + 1];
    const float pjz = p[myidx * 3 + 2];

    // prefetch all gather rows (32 VMEM in flight)
    float xkr[NNS], xvr[NNS];
    #pragma unroll
    for (int k = 0; k < NNS; ++k) {
        const int j = __builtin_amdgcn_readlane(myidx, k);
        xkr[k] = xk[(size_t)j * COUT + lane];
        xvr[k] = xv[(size_t)j * COUT + lane];
    }

    // position-MLP hidden layer for neighbor (lane & 15), all lanes uniform per 16
    const float gx0 = pjx - pix, gx1 = pjy - piy, gx2 = pjz - piz;
    float h0 = fmaf(gx2, wp1[6], fmaf(gx1, wp1[3], gx0 * wp1[0]));
    float h1 = fmaf(gx2, wp1[7], fmaf(gx1, wp1[4], gx0 * wp1[1]));
    float h2 = fmaf(gx2, wp1[8], fmaf(gx1, wp1[5], gx0 * wp1[2]));
    h0 = fmaxf(0.f, fmaf(h0, ap[0], cp[0]));
    h1 = fmaxf(0.f, fmaf(h1, ap[1], cp[1]));
    h2 = fmaxf(0.f, fmaf(h2, ap[2], cp[2]));

    float y[NNS];
    float m = -INFINITY;

    #pragma unroll
    for (int k = 0; k < NNS; ++k) {
        // pr for neighbor k at this channel
        const float hk0 = rdlanef(h0, k);
        const float hk1 = rdlanef(h1, k);
        const float hk2 = rdlanef(h2, k);
        const float pr = fmaf(hk2, wp2_2, fmaf(hk1, wp2_1, fmaf(hk0, wp2_0, bp2c)));
        // BN1 + ReLU of (xk - xq + pr)
        const float wb = fmaxf(0.f, fmaf(xkr[k], a1, fmaf(pr, a1, c1l)));
        xvr[k] += pr;                         // (vg + pr), kept for pass 2
        // 64x8 matvec: mask-free XOR reduce-scatter (slot s ends at this lane)
        float P0 = wb * w1p[0], P1 = wb * w1p[1], P2 = wb * w1p[2], P3 = wb * w1p[3];
        float P4 = wb * w1p[4], P5 = wb * w1p[5], P6 = wb * w1p[6], P7 = wb * w1p[7];
        float Q0 = P0 + __shfl_xor(P4, 32, 64);
        float Q1 = P1 + __shfl_xor(P5, 32, 64);
        float Q2 = P2 + __shfl_xor(P6, 32, 64);
        float Q3 = P3 + __shfl_xor(P7, 32, 64);
        float R0 = Q0 + __shfl_xor(Q2, 16, 64);
        float R1 = Q1 + __shfl_xor(Q3, 16, 64);
        float T  = R0 + __shfl_xor(R1, 8, 64);
        // complete S[s] across the octet residues
        T += __shfl_xor(T, 4, 64);
        T += __shfl_xor(T, 2, 64);
        T += __shfl_xor(T, 1, 64);
        // BN2 + ReLU, slot-s contribution to output-slot r, allreduce over s
        const float wb2 = fmaxf(0.f, fmaf(T, a2s, c2s));
        float z = wb2 * ww2l;
        z += __shfl_xor(z, 8, 64);
        z += __shfl_xor(z, 16, 64);
        z += __shfl_xor(z, 32, 64);
        const float yk = z + bw2r;
        y[k] = yk;
        m = fmaxf(m, yk);
    }

    // pass 2: exact softmax + weighted sum
    float den = 0.f, acc = 0.f;
    #pragma unroll
    for (int k = 0; k < NNS; ++k) {
        const float e = __expf(y[k] - m);
        den += e;
        acc = fmaf(e, xvr[k], acc);
    }
    out[(size_t)i * COUT + lane] = acc / den;
}

extern "C" void kernel_launch(void* const* d_in, const int* in_sizes, int n_in,
                              void* d_out, int out_size, void* d_ws, size_t ws_size,
                              hipStream_t stream) {
    const float* p     = (const float*)d_in[0];
    const float* x     = (const float*)d_in[1];
    const int*   idx   = (const int*)  d_in[2];
    const float* Wq    = (const float*)d_in[3];
    const float* bq    = (const float*)d_in[4];
    const float* Wk    = (const float*)d_in[5];
    const float* bk    = (const float*)d_in[6];
    const float* Wv    = (const float*)d_in[7];
    const float* bv    = (const float*)d_in[8];
    const float* Wp1   = (const float*)d_in[9];
    const float* bp1   = (const float*)d_in[10];
    const float* bnp_g = (const float*)d_in[11];
    const float* bnp_b = (const float*)d_in[12];
    const float* bnp_m = (const float*)d_in[13];
    const float* bnp_v = (const float*)d_in[14];
    const float* Wp2   = (const float*)d_in[15];
    const float* bp2   = (const float*)d_in[16];
    const float* bnw1_g= (const float*)d_in[17];
    const float* bnw1_b= (const float*)d_in[18];
    const float* bnw1_m= (const float*)d_in[19];
    const float* bnw1_v= (const float*)d_in[20];
    const float* Ww1   = (const float*)d_in[21];
    const float* bw1   = (const float*)d_in[22];
    const float* bnw2_g= (const float*)d_in[23];
    const float* bnw2_b= (const float*)d_in[24];
    const float* bnw2_m= (const float*)d_in[25];
    const float* bnw2_v= (const float*)d_in[26];
    const float* Ww2   = (const float*)d_in[27];
    const float* bw2   = (const float*)d_in[28];

    const int n = in_sizes[0] / 3;   // N points

    float* xq = (float*)d_ws;
    float* xk = xq + (size_t)n * COUT;
    float* xv = xk + (size_t)n * COUT;

    hipLaunchKernelGGL(qkv_kernel, dim3(512), dim3(256), 0, stream,
                       x, Wq, bq, Wk, bk, Wv, bv, xq, xk, xv, n);
    hipLaunchKernelGGL(fused_kernel, dim3((n + 3) / 4), dim3(256), 0, stream,
                       p, idx, xq, xk, xv,
                       Wp1, bp1, bnp_g, bnp_b, bnp_m, bnp_v, Wp2, bp2,
                       bnw1_g, bnw1_b, bnw1_m, bnw1_v, Ww1, bw1,
                       bnw2_g, bnw2_b, bnw2_m, bnw2_v, Ww2, bw2,
                       (float*)d_out, n);
}

// Round 6
// 371.597 us; speedup vs baseline: 1.8575x; 1.0876x over previous
//
#include <hip/hip_runtime.h>
#include <math.h>

#define NNS 16
#define CIN 64
#define COUT 64
#define CS 8
#define EPSB 1e-5f

typedef float f32x4 __attribute__((ext_vector_type(4)));
typedef short bf16x8 __attribute__((ext_vector_type(8)));

static __device__ __forceinline__ float rdlanef(float v, int l) {
    return __builtin_bit_cast(float, __builtin_amdgcn_readlane(__builtin_bit_cast(int, v), l));
}

// fp32 -> bf16 with round-to-nearest-even (values are finite; no NaN handling)
static __device__ __forceinline__ short f2bf(float x) {
    unsigned b = __builtin_bit_cast(unsigned, x);
    b += 0x7FFFu + ((b >> 16) & 1u);
    return (short)(b >> 16);
}

// ---------------- Kernel 1: QKV projection via MFMA ----------------
// (n x 64) @ (64 x 192) in bf16 MFMA, fp32 accumulate. One wave per 16-row
// chunk; all 3 weight matrices live as bf16 B-frags (96 VGPRs); bias folded
// into the accumulator init. 24 MFMAs per chunk. No LDS, no readlane.
__global__ __launch_bounds__(256, 2) void qkv_kernel(
    const float* __restrict__ x,
    const float* __restrict__ Wq, const float* __restrict__ bq,
    const float* __restrict__ Wk, const float* __restrict__ bk,
    const float* __restrict__ Wv, const float* __restrict__ bv,
    float* __restrict__ xq, float* __restrict__ xk, float* __restrict__ xv,
    int n)
{
    const int lane = threadIdx.x & 63;
    const int w    = threadIdx.x >> 6;
    const int col  = lane & 15;   // B/C col within 16-tile; A row selector
    const int kg   = lane >> 4;   // k-group 0..3

    // ---- one-time: weights -> bf16 B-frags, biases per tile ----
    // B-frag layout (16x16x32): lane holds B[k][col], k = 32h + kg*8 + j
    const float* Wm[3] = {Wq, Wk, Wv};
    const float* bm[3] = {bq, bk, bv};
    bf16x8 Bf[3][4][2];
    float  bias[3][4];
    #pragma unroll
    for (int m = 0; m < 3; ++m) {
        #pragma unroll
        for (int t = 0; t < 4; ++t) {
            bias[m][t] = bm[m][t * 16 + col];
            #pragma unroll
            for (int h = 0; h < 2; ++h) {
                bf16x8 f;
                #pragma unroll
                for (int j = 0; j < 8; ++j) {
                    const int k = h * 32 + kg * 8 + j;
                    f[j] = f2bf(Wm[m][k * COUT + t * 16 + col]);
                }
                Bf[m][t][h] = f;
            }
        }
    }

    const int nchunks = (n + 63) >> 6;
    for (int cb = blockIdx.x; cb < nchunks; cb += gridDim.x) {
        const int i0 = cb * 64 + w * 16;   // this wave's 16-row base
        if (i0 >= n) continue;

        // ---- A-frags: rows i0+col, k = kg*8..kg*8+7 (+32 for frag 1) ----
        const int r  = i0 + col;
        const int rc = (r < n) ? r : (n - 1);   // clamp (rows >= n never stored)
        const float* xr = x + (size_t)rc * CIN + kg * 8;
        const f32x4 a0 = *(const f32x4*)(xr);
        const f32x4 a1 = *(const f32x4*)(xr + 4);
        const f32x4 a2 = *(const f32x4*)(xr + 32);
        const f32x4 a3 = *(const f32x4*)(xr + 36);
        bf16x8 A0, A1;
        #pragma unroll
        for (int j = 0; j < 4; ++j) {
            A0[j]     = f2bf(a0[j]);
            A0[j + 4] = f2bf(a1[j]);
            A1[j]     = f2bf(a2[j]);
            A1[j + 4] = f2bf(a3[j]);
        }

        // ---- accumulate: C init = bias, 2 MFMAs per (matrix, tile) ----
        f32x4 acc[3][4];
        #pragma unroll
        for (int m = 0; m < 3; ++m)
            #pragma unroll
            for (int t = 0; t < 4; ++t) {
                const float bv_ = bias[m][t];
                acc[m][t] = (f32x4){bv_, bv_, bv_, bv_};
            }
        #pragma unroll
        for (int m = 0; m < 3; ++m)
            #pragma unroll
            for (int t = 0; t < 4; ++t) {
                acc[m][t] = __builtin_amdgcn_mfma_f32_16x16x32_bf16(A0, Bf[m][t][0], acc[m][t], 0, 0, 0);
                acc[m][t] = __builtin_amdgcn_mfma_f32_16x16x32_bf16(A1, Bf[m][t][1], acc[m][t], 0, 0, 0);
            }

        // ---- store: C/D row = kg*4 + e, col = t*16 + col ----
        float* const om[3] = {xq, xk, xv};
        #pragma unroll
        for (int m = 0; m < 3; ++m)
            #pragma unroll
            for (int t = 0; t < 4; ++t)
                #pragma unroll
                for (int e = 0; e < 4; ++e) {
                    const int row = i0 + kg * 4 + e;
                    if (row < n)
                        om[m][(size_t)row * COUT + t * 16 + col] = acc[m][t][e];
                }
    }
}

// ---------------- Kernel 2: fused neighbor attention (unchanged) ----------------
__global__ __launch_bounds__(256) void fused_kernel(
    const float* __restrict__ p, const int* __restrict__ idx,
    const float* __restrict__ xq, const float* __restrict__ xk, const float* __restrict__ xv,
    const float* __restrict__ Wp1, const float* __restrict__ bp1,
    const float* __restrict__ bnp_g, const float* __restrict__ bnp_b,
    const float* __restrict__ bnp_m, const float* __restrict__ bnp_v,
    const float* __restrict__ Wp2, const float* __restrict__ bp2,
    const float* __restrict__ bnw1_g, const float* __restrict__ bnw1_b,
    const float* __restrict__ bnw1_m, const float* __restrict__ bnw1_v,
    const float* __restrict__ Ww1, const float* __restrict__ bw1,
    const float* __restrict__ bnw2_g, const float* __restrict__ bnw2_b,
    const float* __restrict__ bnw2_m, const float* __restrict__ bnw2_v,
    const float* __restrict__ Ww2, const float* __restrict__ bw2,
    float* __restrict__ out, int n)
{
    const int lane = threadIdx.x & 63;
    const int s    = (lane >> 3) & 7;   // owned slot after reduce-scatter
    const int r    = lane & 7;          // output-slot this channel consumes (c % 8)

    // ---- wave-uniform params (SGPRs) ----
    float wp1[9];
    #pragma unroll
    for (int t = 0; t < 9; ++t) wp1[t] = Wp1[t];
    float ap[3], cp[3];
    #pragma unroll
    for (int t = 0; t < 3; ++t) {
        const float a = bnp_g[t] * rsqrtf(bnp_v[t] + EPSB);
        ap[t] = a;
        cp[t] = (bp1[t] - bnp_m[t]) * a + bnp_b[t];
    }
    // ---- per-lane params ----
    const float wp2_0 = Wp2[0 * COUT + lane];
    const float wp2_1 = Wp2[1 * COUT + lane];
    const float wp2_2 = Wp2[2 * COUT + lane];
    const float bp2c  = bp2[lane];
    const float a1 = bnw1_g[lane] * rsqrtf(bnw1_v[lane] + EPSB);
    const float c1 = bnw1_b[lane] - bnw1_m[lane] * a1;
    // pre-permuted Ww1: position t holds slot (t ^ s)
    float w1p[8];
    #pragma unroll
    for (int t = 0; t < 8; ++t) w1p[t] = Ww1[lane * CS + (t ^ s)];
    // slot-s BN2 params + Ww2[s][r] == Ww2[lane]
    const float a2s = bnw2_g[s] * rsqrtf(bnw2_v[s] + EPSB);
    const float c2s = bnw2_b[s] + (bw1[s] - bnw2_m[s]) * a2s;
    const float ww2l = Ww2[lane];
    const float bw2r = bw2[r];

    const int wid = __builtin_amdgcn_readfirstlane((int)(threadIdx.x >> 6));
    const int i = blockIdx.x * 4 + wid;
    if (i >= n) return;

    const int myidx = idx[i * NNS + (lane & 15)];
    const float xqc = xq[(size_t)i * COUT + lane];
    const float c1l = c1 - a1 * xqc;    // fold -xq into the BN1 shift
    const float pix = p[i * 3 + 0];
    const float piy = p[i * 3 + 1];
    const float piz = p[i * 3 + 2];

    // gather neighbor positions (lane k holds neighbor k&15's data)
    const float pjx = p[myidx * 3 + 0];
    const float pjy = p[myidx * 3 + 1];
    const float pjz = p[myidx * 3 + 2];

    // prefetch all gather rows (32 VMEM in flight)
    float xkr[NNS], xvr[NNS];
    #pragma unroll
    for (int k = 0; k < NNS; ++k) {
        const int j = __builtin_amdgcn_readlane(myidx, k);
        xkr[k] = xk[(size_t)j * COUT + lane];
        xvr[k] = xv[(size_t)j * COUT + lane];
    }

    // position-MLP hidden layer for neighbor (lane & 15), all lanes uniform per 16
    const float gx0 = pjx - pix, gx1 = pjy - piy, gx2 = pjz - piz;
    float h0 = fmaf(gx2, wp1[6], fmaf(gx1, wp1[3], gx0 * wp1[0]));
    float h1 = fmaf(gx2, wp1[7], fmaf(gx1, wp1[4], gx0 * wp1[1]));
    float h2 = fmaf(gx2, wp1[8], fmaf(gx1, wp1[5], gx0 * wp1[2]));
    h0 = fmaxf(0.f, fmaf(h0, ap[0], cp[0]));
    h1 = fmaxf(0.f, fmaf(h1, ap[1], cp[1]));
    h2 = fmaxf(0.f, fmaf(h2, ap[2], cp[2]));

    float y[NNS];
    float m = -INFINITY;

    #pragma unroll
    for (int k = 0; k < NNS; ++k) {
        // pr for neighbor k at this channel
        const float hk0 = rdlanef(h0, k);
        const float hk1 = rdlanef(h1, k);
        const float hk2 = rdlanef(h2, k);
        const float pr = fmaf(hk2, wp2_2, fmaf(hk1, wp2_1, fmaf(hk0, wp2_0, bp2c)));
        // BN1 + ReLU of (xk - xq + pr)
        const float wb = fmaxf(0.f, fmaf(xkr[k], a1, fmaf(pr, a1, c1l)));
        xvr[k] += pr;                         // (vg + pr), kept for pass 2
        // 64x8 matvec: mask-free XOR reduce-scatter (slot s ends at this lane)
        float P0 = wb * w1p[0], P1 = wb * w1p[1], P2 = wb * w1p[2], P3 = wb * w1p[3];
        float P4 = wb * w1p[4], P5 = wb * w1p[5], P6 = wb * w1p[6], P7 = wb * w1p[7];
        float Q0 = P0 + __shfl_xor(P4, 32, 64);
        float Q1 = P1 + __shfl_xor(P5, 32, 64);
        float Q2 = P2 + __shfl_xor(P6, 32, 64);
        float Q3 = P3 + __shfl_xor(P7, 32, 64);
        float R0 = Q0 + __shfl_xor(Q2, 16, 64);
        float R1 = Q1 + __shfl_xor(Q3, 16, 64);
        float T  = R0 + __shfl_xor(R1, 8, 64);
        // complete S[s] across the octet residues
        T += __shfl_xor(T, 4, 64);
        T += __shfl_xor(T, 2, 64);
        T += __shfl_xor(T, 1, 64);
        // BN2 + ReLU, slot-s contribution to output-slot r, allreduce over s
        const float wb2 = fmaxf(0.f, fmaf(T, a2s, c2s));
        float z = wb2 * ww2l;
        z += __shfl_xor(z, 8, 64);
        z += __shfl_xor(z, 16, 64);
        z += __shfl_xor(z, 32, 64);
        const float yk = z + bw2r;
        y[k] = yk;
        m = fmaxf(m, yk);
    }

    // pass 2: exact softmax + weighted sum
    float den = 0.f, acc = 0.f;
    #pragma unroll
    for (int k = 0; k < NNS; ++k) {
        const float e = __expf(y[k] - m);
        den += e;
        acc = fmaf(e, xvr[k], acc);
    }
    out[(size_t)i * COUT + lane] = acc / den;
}

extern "C" void kernel_launch(void* const* d_in, const int* in_sizes, int n_in,
                              void* d_out, int out_size, void* d_ws, size_t ws_size,
                              hipStream_t stream) {
    const float* p     = (const float*)d_in[0];
    const float* x     = (const float*)d_in[1];
    const int*   idx   = (const int*)  d_in[2];
    const float* Wq    = (const float*)d_in[3];
    const float* bq    = (const float*)d_in[4];
    const float* Wk    = (const float*)d_in[5];
    const float* bk    = (const float*)d_in[6];
    const float* Wv    = (const float*)d_in[7];
    const float* bv    = (const float*)d_in[8];
    const float* Wp1   = (const float*)d_in[9];
    const float* bp1   = (const float*)d_in[10];
    const float* bnp_g = (const float*)d_in[11];
    const float* bnp_b = (const float*)d_in[12];
    const float* bnp_m = (const float*)d_in[13];
    const float* bnp_v = (const float*)d_in[14];
    const float* Wp2   = (const float*)d_in[15];
    const float* bp2   = (const float*)d_in[16];
    const float* bnw1_g= (const float*)d_in[17];
    const float* bnw1_b= (const float*)d_in[18];
    const float* bnw1_m= (const float*)d_in[19];
    const float* bnw1_v= (const float*)d_in[20];
    const float* Ww1   = (const float*)d_in[21];
    const float* bw1   = (const float*)d_in[22];
    const float* bnw2_g= (const float*)d_in[23];
    const float* bnw2_b= (const float*)d_in[24];
    const float* bnw2_m= (const float*)d_in[25];
    const float* bnw2_v= (const float*)d_in[26];
    const float* Ww2   = (const float*)d_in[27];
    const float* bw2   = (const float*)d_in[28];

    const int n = in_sizes[0] / 3;   // N points

    float* xq = (float*)d_ws;
    float* xk = xq + (size_t)n * COUT;
    float* xv = xk + (size_t)n * COUT;

    hipLaunchKernelGGL(qkv_kernel, dim3(512), dim3(256), 0, stream,
                       x, Wq, bq, Wk, bk, Wv, bv, xq, xk, xv, n);
    hipLaunchKernelGGL(fused_kernel, dim3((n + 3) / 4), dim3(256), 0, stream,
                       p, idx, xq, xk, xv,
                       Wp1, bp1, bnp_g, bnp_b, bnp_m, bnp_v, Wp2, bp2,
                       bnw1_g, bnw1_b, bnw1_m, bnw1_v, Ww1, bw1,
                       bnw2_g, bnw2_b, bnw2_m, bnw2_v, Ww2, bw2,
                       (float*)d_out, n);
}

// Round 10
// 290.730 us; speedup vs baseline: 2.3742x; 1.2782x over previous
//
#include <hip/hip_runtime.h>
#include <math.h>

#define NNS 16
#define CIN 64
#define COUT 64
#define CS 8
#define EPSB 1e-5f

typedef float f32x4 __attribute__((ext_vector_type(4)));
typedef short bf16x8 __attribute__((ext_vector_type(8)));

static __device__ __forceinline__ float rdlanef(float v, int l) {
    return __builtin_bit_cast(float, __builtin_amdgcn_readlane(__builtin_bit_cast(int, v), l));
}

// DPP cross-lane move (VALU pipe, not DS pipe).
// 0xB1 = quad_perm [1,0,3,2] (xor1), 0x4E = quad_perm [2,3,0,1] (xor2),
// 0x128 = row_ror:8 (== xor8 within a 16-lane row), 0x141 = row_half_mirror (xor7).
template<int CTRL>
static __device__ __forceinline__ float dppf(float v) {
    return __builtin_bit_cast(float,
        __builtin_amdgcn_update_dpp(0, __builtin_bit_cast(int, v), CTRL, 0xf, 0xf, true));
}

// fp32 -> bf16 round-to-nearest-even (finite values)
static __device__ __forceinline__ short f2bf(float x) {
    unsigned b = __builtin_bit_cast(unsigned, x);
    b += 0x7FFFu + ((b >> 16) & 1u);
    return (short)(b >> 16);
}

// ---------------- Kernel 1: QKV projection via MFMA, B-frags in LDS ----------------
// (n x 64) @ (64 x 192) bf16 MFMA, fp32 accum. Weights staged ONCE per block in
// LDS, frag-major: each lane's B-fragment is one contiguous ds_read_b128.
__global__ __launch_bounds__(256, 2) void qkv_kernel(
    const float* __restrict__ x,
    const float* __restrict__ Wq, const float* __restrict__ bq,
    const float* __restrict__ Wk, const float* __restrict__ bk,
    const float* __restrict__ Wv, const float* __restrict__ bv,
    float* __restrict__ xq, float* __restrict__ xk, float* __restrict__ xv,
    int n)
{
    __shared__ short Wl[24 * 512];   // 24 frags x 512 bf16 = 24 KB

    const int lane = threadIdx.x & 63;
    const int w    = threadIdx.x >> 6;
    const int col  = lane & 15;   // B/C col within 16-tile; A row selector
    const int kg   = lane >> 4;   // k-group 0..3

    // frag (m,t,h): lane l holds B[k][t*16+(l&15)], k = h*32 + (l>>4)*8 + j
    const float* const Wm[3] = {Wq, Wk, Wv};
    #pragma unroll
    for (int f = 0; f < 24; ++f) {
        const int m = f >> 3, t = (f >> 1) & 3, h = f & 1;
        #pragma unroll
        for (int rep = 0; rep < 2; ++rep) {
            const int e = rep * 256 + (int)threadIdx.x;   // 0..511
            const int l = e >> 3, j = e & 7;
            const int k = h * 32 + (l >> 4) * 8 + j;
            Wl[f * 512 + e] = f2bf(Wm[m][k * COUT + t * 16 + (l & 15)]);
        }
    }
    __syncthreads();

    const float* const bm[3] = {bq, bk, bv};
    float bias[3][4];
    #pragma unroll
    for (int m = 0; m < 3; ++m)
        #pragma unroll
        for (int t = 0; t < 4; ++t)
            bias[m][t] = bm[m][t * 16 + col];

    float* const om[3] = {xq, xk, xv};
    const int nchunks = (n + 63) >> 6;
    for (int cb = blockIdx.x; cb < nchunks; cb += gridDim.x) {
        const int i0 = cb * 64 + w * 16;
        if (i0 >= n) continue;

        const int r  = i0 + col;
        const int rc = (r < n) ? r : (n - 1);
        const float* xr = x + (size_t)rc * CIN + kg * 8;
        const f32x4 a0 = *(const f32x4*)(xr);
        const f32x4 a1 = *(const f32x4*)(xr + 4);
        const f32x4 a2 = *(const f32x4*)(xr + 32);
        const f32x4 a3 = *(const f32x4*)(xr + 36);
        bf16x8 A0, A1;
        #pragma unroll
        for (int j = 0; j < 4; ++j) {
            A0[j]     = f2bf(a0[j]);
            A0[j + 4] = f2bf(a1[j]);
            A1[j]     = f2bf(a2[j]);
            A1[j + 4] = f2bf(a3[j]);
        }

        f32x4 acc[3][4];
        #pragma unroll
        for (int m = 0; m < 3; ++m)
            #pragma unroll
            for (int t = 0; t < 4; ++t) {
                const float b_ = bias[m][t];
                acc[m][t] = (f32x4){b_, b_, b_, b_};
            }
        #pragma unroll
        for (int m = 0; m < 3; ++m)
            #pragma unroll
            for (int t = 0; t < 4; ++t) {
                const int f = (m * 4 + t) * 2;
                const bf16x8 B0 = *(const bf16x8*)&Wl[(f + 0) * 512 + lane * 8];
                const bf16x8 B1 = *(const bf16x8*)&Wl[(f + 1) * 512 + lane * 8];
                acc[m][t] = __builtin_amdgcn_mfma_f32_16x16x32_bf16(A0, B0, acc[m][t], 0, 0, 0);
                acc[m][t] = __builtin_amdgcn_mfma_f32_16x16x32_bf16(A1, B1, acc[m][t], 0, 0, 0);
            }

        #pragma unroll
        for (int m = 0; m < 3; ++m)
            #pragma unroll
            for (int t = 0; t < 4; ++t)
                #pragma unroll
                for (int e = 0; e < 4; ++e) {
                    const int row = i0 + kg * 4 + e;
                    if (row < n)
                        om[m][(size_t)row * COUT + t * 16 + col] = acc[m][t][e];
                }
    }
}

// ---------------- Kernel 2: fused neighbor attention, DPP butterfly ----------------
// One wave per point, lane = channel. Reduce-scatter stage order xor8 (DPP),
// xor16, xor32; completion xor1/xor2 (quad_perm) + xor4 (half_mirror after quad
// symmetry); z-allreduce xor8 (DPP) + xor16/32 shuffles. DS-pipe ops per
// neighbor: 13 -> 5.
__global__ __launch_bounds__(256) void fused_kernel(
    const float* __restrict__ p, const int* __restrict__ idx,
    const float* __restrict__ xq, const float* __restrict__ xk, const float* __restrict__ xv,
    const float* __restrict__ Wp1, const float* __restrict__ bp1,
    const float* __restrict__ bnp_g, const float* __restrict__ bnp_b,
    const float* __restrict__ bnp_m, const float* __restrict__ bnp_v,
    const float* __restrict__ Wp2, const float* __restrict__ bp2,
    const float* __restrict__ bnw1_g, const float* __restrict__ bnw1_b,
    const float* __restrict__ bnw1_m, const float* __restrict__ bnw1_v,
    const float* __restrict__ Ww1, const float* __restrict__ bw1,
    const float* __restrict__ bnw2_g, const float* __restrict__ bnw2_b,
    const float* __restrict__ bnw2_m, const float* __restrict__ bnw2_v,
    const float* __restrict__ Ww2, const float* __restrict__ bw2,
    float* __restrict__ out, int n)
{
    const int lane = threadIdx.x & 63;
    const int s    = (lane >> 3) & 7;   // owned slot after reduce-scatter
    const int r    = lane & 7;          // output-slot this channel consumes (c % 8)

    // ---- wave-uniform params (SGPRs) ----
    float wp1[9];
    #pragma unroll
    for (int t = 0; t < 9; ++t) wp1[t] = Wp1[t];
    float ap[3], cp[3];
    #pragma unroll
    for (int t = 0; t < 3; ++t) {
        const float a = bnp_g[t] * rsqrtf(bnp_v[t] + EPSB);
        ap[t] = a;
        cp[t] = (bp1[t] - bnp_m[t]) * a + bnp_b[t];
    }
    // ---- per-lane params ----
    const float wp2_0 = Wp2[0 * COUT + lane];
    const float wp2_1 = Wp2[1 * COUT + lane];
    const float wp2_2 = Wp2[2 * COUT + lane];
    const float bp2c  = bp2[lane];
    const float a1 = bnw1_g[lane] * rsqrtf(bnw1_v[lane] + EPSB);
    const float c1 = bnw1_b[lane] - bnw1_m[lane] * a1;
    // pre-permuted Ww1: position t holds slot (t ^ s)  (stage-order invariant)
    float w1p[8];
    #pragma unroll
    for (int t = 0; t < 8; ++t) w1p[t] = Ww1[lane * CS + (t ^ s)];
    // slot-s BN2 params + Ww2[s][r] == Ww2[lane]
    const float a2s = bnw2_g[s] * rsqrtf(bnw2_v[s] + EPSB);
    const float c2s = bnw2_b[s] + (bw1[s] - bnw2_m[s]) * a2s;
    const float ww2l = Ww2[lane];
    const float bw2r = bw2[r];

    const int wid = __builtin_amdgcn_readfirstlane((int)(threadIdx.x >> 6));
    const int i = blockIdx.x * 4 + wid;
    if (i >= n) return;

    const int myidx = idx[i * NNS + (lane & 15)];
    const float xqc = xq[(size_t)i * COUT + lane];
    const float c1l = c1 - a1 * xqc;    // fold -xq into the BN1 shift
    const float pix = p[i * 3 + 0];
    const float piy = p[i * 3 + 1];
    const float piz = p[i * 3 + 2];

    const float pjx = p[myidx * 3 + 0];
    const float pjy = p[myidx * 3 + 1];
    const float pjz = p[myidx * 3 + 2];

    // prefetch all gather rows (32 VMEM in flight)
    float xkr[NNS], xvr[NNS];
    #pragma unroll
    for (int k = 0; k < NNS; ++k) {
        const int j = __builtin_amdgcn_readlane(myidx, k);
        xkr[k] = xk[(size_t)j * COUT + lane];
        xvr[k] = xv[(size_t)j * COUT + lane];
    }

    // position-MLP hidden layer for neighbor (lane & 15)
    const float gx0 = pjx - pix, gx1 = pjy - piy, gx2 = pjz - piz;
    float h0 = fmaf(gx2, wp1[6], fmaf(gx1, wp1[3], gx0 * wp1[0]));
    float h1 = fmaf(gx2, wp1[7], fmaf(gx1, wp1[4], gx0 * wp1[1]));
    float h2 = fmaf(gx2, wp1[8], fmaf(gx1, wp1[5], gx0 * wp1[2]));
    h0 = fmaxf(0.f, fmaf(h0, ap[0], cp[0]));
    h1 = fmaxf(0.f, fmaf(h1, ap[1], cp[1]));
    h2 = fmaxf(0.f, fmaf(h2, ap[2], cp[2]));

    float y[NNS];
    float m = -INFINITY;

    #pragma unroll
    for (int k = 0; k < NNS; ++k) {
        const float hk0 = rdlanef(h0, k);
        const float hk1 = rdlanef(h1, k);
        const float hk2 = rdlanef(h2, k);
        const float pr = fmaf(hk2, wp2_2, fmaf(hk1, wp2_1, fmaf(hk0, wp2_0, bp2c)));
        const float wb = fmaxf(0.f, fmaf(xkr[k], a1, fmaf(pr, a1, c1l)));
        xvr[k] += pr;                         // (vg + pr), kept for pass 2
        // products for the (64 -> 8) matvec
        const float P0 = wb * w1p[0], P1 = wb * w1p[1], P2 = wb * w1p[2], P3 = wb * w1p[3];
        const float P4 = wb * w1p[4], P5 = wb * w1p[5], P6 = wb * w1p[6], P7 = wb * w1p[7];
        // stage 1 (t-bit0 <-> lane-bit3, xor8): DPP row_ror:8, 4 adds, 0 DS ops
        const float Q0 = P0 + dppf<0x128>(P1);
        const float Q2 = P2 + dppf<0x128>(P3);
        const float Q4 = P4 + dppf<0x128>(P5);
        const float Q6 = P6 + dppf<0x128>(P7);
        // stage 2 (t-bit1 <-> lane-bit4, xor16): 2 shuffles
        const float R0 = Q0 + __shfl_xor(Q2, 16, 64);
        const float R4 = Q4 + __shfl_xor(Q6, 16, 64);
        // stage 3 (t-bit2 <-> lane-bit5, xor32): 1 shuffle
        float T = R0 + __shfl_xor(R4, 32, 64);
        // completion over residue bits 0-2: all DPP
        T += dppf<0xB1>(T);    // xor1 (quad_perm)
        T += dppf<0x4E>(T);    // xor2 (quad_perm)
        T += dppf<0x141>(T);   // half_mirror = xor7 == xor4 after quad symmetry
        // BN2 + ReLU, slot-s contribution to output-slot r, allreduce over s
        const float wb2 = fmaxf(0.f, fmaf(T, a2s, c2s));
        float z = wb2 * ww2l;
        z += dppf<0x128>(z);          // xor8 (DPP)
        z += __shfl_xor(z, 16, 64);
        z += __shfl_xor(z, 32, 64);
        const float yk = z + bw2r;
        y[k] = yk;
        m = fmaxf(m, yk);
    }

    // pass 2: exact softmax + weighted sum
    float den = 0.f, acc = 0.f;
    #pragma unroll
    for (int k = 0; k < NNS; ++k) {
        const float e = __expf(y[k] - m);
        den += e;
        acc = fmaf(e, xvr[k], acc);
    }
    out[(size_t)i * COUT + lane] = acc / den;
}

extern "C" void kernel_launch(void* const* d_in, const int* in_sizes, int n_in,
                              void* d_out, int out_size, void* d_ws, size_t ws_size,
                              hipStream_t stream) {
    const float* p     = (const float*)d_in[0];
    const float* x     = (const float*)d_in[1];
    const int*   idx   = (const int*)  d_in[2];
    const float* Wq    = (const float*)d_in[3];
    const float* bq    = (const float*)d_in[4];
    const float* Wk    = (const float*)d_in[5];
    const float* bk    = (const float*)d_in[6];
    const float* Wv    = (const float*)d_in[7];
    const float* bv    = (const float*)d_in[8];
    const float* Wp1   = (const float*)d_in[9];
    const float* bp1   = (const float*)d_in[10];
    const float* bnp_g = (const float*)d_in[11];
    const float* bnp_b = (const float*)d_in[12];
    const float* bnp_m = (const float*)d_in[13];
    const float* bnp_v = (const float*)d_in[14];
    const float* Wp2   = (const float*)d_in[15];
    const float* bp2   = (const float*)d_in[16];
    const float* bnw1_g= (const float*)d_in[17];
    const float* bnw1_b= (const float*)d_in[18];
    const float* bnw1_m= (const float*)d_in[19];
    const float* bnw1_v= (const float*)d_in[20];
    const float* Ww1   = (const float*)d_in[21];
    const float* bw1   = (const float*)d_in[22];
    const float* bnw2_g= (const float*)d_in[23];
    const float* bnw2_b= (const float*)d_in[24];
    const float* bnw2_m= (const float*)d_in[25];
    const float* bnw2_v= (const float*)d_in[26];
    const float* Ww2   = (const float*)d_in[27];
    const float* bw2   = (const float*)d_in[28];

    const int n = in_sizes[0] / 3;   // N points

    float* xq = (float*)d_ws;
    float* xk = xq + (size_t)n * COUT;
    float* xv = xk + (size_t)n * COUT;

    hipLaunchKernelGGL(qkv_kernel, dim3(512), dim3(256), 0, stream,
                       x, Wq, bq, Wk, bk, Wv, bv, xq, xk, xv, n);
    hipLaunchKernelGGL(fused_kernel, dim3((n + 3) / 4), dim3(256), 0, stream,
                       p, idx, xq, xk, xv,
                       Wp1, bp1, bnp_g, bnp_b, bnp_m, bnp_v, Wp2, bp2,
                       bnw1_g, bnw1_b, bnw1_m, bnw1_v, Ww1, bw1,
                       bnw2_g, bnw2_b, bnw2_m, bnw2_v, Ww2, bw2,
                       (float*)d_out, n);
}